// Round 11
// baseline (1378.654 us; speedup 1.0000x reference)
//
#include <hip/hip_runtime.h>
#include <math.h>

#define GRPO_BETA 0.1f

constexpr int BM = 128;    // rows per block tile
constexpr int BN = 256;    // vocab cols per block tile (chunk width)
constexpr int BK = 32;     // k-slab; LDS W rows hold 2 slabs (128B, dbuf by bit6)

typedef __attribute__((ext_vector_type(4))) float   f32x4;
typedef __attribute__((ext_vector_type(8))) __bf16  bf16x8;

// NaN-safe exp for lse merges: args expected <= 0; fminf(NaN,0)=0.
__device__ __forceinline__ float sexp_fast(float a) { return __expf(fminf(a, 0.f)); }
__device__ __forceinline__ float sexp(float a)      { return expf(fminf(a, 0.f)); }

__device__ __forceinline__ bf16x8 cvt8(float4 a, float4 b) {
  bf16x8 r;
  r[0] = (__bf16)a.x; r[1] = (__bf16)a.y; r[2] = (__bf16)a.z; r[3] = (__bf16)a.w;
  r[4] = (__bf16)b.x; r[5] = (__bf16)b.y; r[6] = (__bf16)b.z; r[7] = (__bf16)b.w;
  return r;
}

// barrier WITHOUT vmcnt drain: LDS writes made visible (lgkmcnt), global
// prefetch loads stay in flight across the barrier (T4-minimum).
__device__ __forceinline__ void bar_lgkm() {
  asm volatile("s_waitcnt lgkmcnt(0)\n\ts_barrier" ::: "memory");
}

// ---------------------------------------------------------------------------
// Kernel 0: f32 -> bf16 conversion (grid-stride, 16B loads x2 -> 16B store).
// ---------------------------------------------------------------------------
__global__ __launch_bounds__(256)
void cvt_bf16_kernel(const float* __restrict__ src, __bf16* __restrict__ dst,
                     long long n8)
{
  long long i = (long long)blockIdx.x * blockDim.x + threadIdx.x;
  const long long stride = (long long)gridDim.x * blockDim.x;
  for (; i < n8; i += stride) {
    const float4 a = *reinterpret_cast<const float4*>(src + i * 8);
    const float4 b = *reinterpret_cast<const float4*>(src + i * 8 + 4);
    *reinterpret_cast<bf16x8*>(dst + i * 8) = cvt8(a, b);
  }
}

// ---------------------------------------------------------------------------
// Kernel 1: FUSED policy+ref bf16-MFMA GEMM (logits = A[M,K] x W[V,K]^T) with
// per-row per-256-col-chunk reductions.
// grid = 2*gx*NC; after XCD remap, block PARITY selects policy vs ref.
// KEY CHANGE (r11): A-fragments are loaded DIRECTLY FROM GLOBAL (L1/L2-hit;
// per-block A slice is 8 KB/K-step), not staged through LDS. The MFMA
// A-operand layout (row=lane&15, k=(lane>>4)*8+[0..8)) is 16B-contiguous per
// lane -> one global_load_dwordx4 per fragment. This cuts LDS traffic per
// block-K-step from 88 KB to 48 KB (the round-10 bottleneck: LDS pipe ~56%
// of kernel time) and moves A to the idle vector-memory path. A-frag loads
// are per-wave software-pipelined (afA/afB double buffer, issued one k-slab
// ahead, no barrier involvement). W stays LDS-staged (streamed, shared).
// LDS: W only, rows 128B = 2 k-slabs (parity bit 6), XOR swizzle
// byte x of row r at r*128 + (x ^ ((r&7)<<4)); 16B-granule staging writes.
// Pipeline per K-step s (ONE lgkm-barrier per step):
//   issue A-frags(s+1) | MFMA(half s&1) | stage W regs(s+1) -> other half |
//   issue W loads (s+2) | bar.
// CVT=true: f32 inputs, convert in-flight (fallback). FULL: V % BN == 0.
// ---------------------------------------------------------------------------
template <bool CVT, bool FULL>
__global__ __launch_bounds__(512, 4)
void fused_gemm_reduce(const float* __restrict__ AfP, const float* __restrict__ WfP,
                       const float* __restrict__ AfR, const float* __restrict__ WfR,
                       const __bf16* __restrict__ AhP, const __bf16* __restrict__ WhP,
                       const __bf16* __restrict__ AhR, const __bf16* __restrict__ WhR,
                       float* __restrict__ partP, float* __restrict__ partR,
                       int M, int K, int V, int NC, int NL, int gx)
{
  __shared__ __align__(16) unsigned short lds_w[BN * 64];   // 32 KB (2 slabs)
  __shared__ __align__(16) float4 lds_red[BM * 4];          // 8 KB

  const int tid  = threadIdx.x;
  const int lane = tid & 63;
  const int wave = tid >> 6;      // 0..7
  const int wm   = wave >> 2;     // 0..1  (M half)
  const int wn   = wave & 3;      // 0..3  (N quarter)
  const int l15  = lane & 15;
  const int q    = lane >> 4;     // 0..3

  // ---- XCD-aware block remap (bijective when nb % 8 == 0) + parity split ----
  const int nb  = gridDim.x;
  int wl = blockIdx.x;
  if ((nb & 7) == 0) wl = (wl & 7) * (nb >> 3) + (wl >> 3);
  const bool isPol = (wl & 1) == 0;     // even -> policy, odd -> ref
  const int  w2    = wl >> 1;
  const int  bx    = w2 % gx;
  const int  chunk = w2 / gx;
  const int  row0  = bx * BM;

  // uniform input selects
  const float*  Af = isPol ? AfP : AfR;
  const float*  Wf = isPol ? WfP : WfR;
  const __bf16* Ah = isPol ? AhP : AhR;
  const __bf16* Wh = isPol ? WhP : WhR;

  // ---- W staging map: lane covers 8 k-elems (16B granule) of one row ----
  const int t3 = tid & 3;
  const int r4 = tid >> 2;        // 0..127
  const int stw = ((t3 * 16) ^ ((r4 & 7) << 4));

  // ---- A-fragment global element offsets (frag f, k-slab 0) ----
  int afo[4];
#pragma unroll
  for (int f = 0; f < 4; ++f)
    afo[f] = min(row0 + wm * 64 + f * 16 + l15, M - 1) * K + q * 8;

  // ---- W fragment LDS byte offsets (slab parity = bit 6; frag fn adds 2048) ----
  const int swzr  = ((q * 16) ^ ((l15 & 7) << 4));
  const int woff0 = (wn * 64 + l15) * 128 + swzr;

  // running per-row records (threads 0..127 own local row = tid)
  float rm = -INFINITY, rse = 0.f, rsum = 0.f;
  int   ridx = 0x7fffffff;

  const int NS = K / BK;

  for (int sub = 0; sub < NL; ++sub) {
    const int v0 = (chunk * NL + sub) * BN;
    if (v0 >= V) break;

    int wro[2];
#pragma unroll
    for (int i = 0; i < 2; ++i)
      wro[i] = min(v0 + r4 + 128 * i, V - 1) * K + t3 * 8;

    f32x4 acc[4][4];
#pragma unroll
    for (int i = 0; i < 4; ++i)
#pragma unroll
      for (int j = 0; j < 4; ++j) acc[i][j] = (f32x4){0.f, 0.f, 0.f, 0.f};

    // prefetch registers
    bf16x8 wH[2];               // W slab prefetch (bf16 path)
    float4 wF[2][2];            // W slab prefetch (f32 path)
    bf16x8 afA[4], afB[4];      // A-frag double buffer (bf16 path)
    float4 afFA[4][2], afFB[4][2];  // A-frag double buffer (f32 path)

    // ---- prologue: W slab0 -> LDS half0; A-frags slab0; W slab1 regs ----
    if constexpr (CVT) {
#pragma unroll
      for (int i = 0; i < 2; ++i) {
        const float4 w0 = *reinterpret_cast<const float4*>(Wf + wro[i]);
        const float4 w1 = *reinterpret_cast<const float4*>(Wf + wro[i] + 4);
        *reinterpret_cast<bf16x8*>(reinterpret_cast<char*>(lds_w) + (r4 + 128 * i) * 128 + stw) =
            cvt8(w0, w1);
      }
#pragma unroll
      for (int f = 0; f < 4; ++f) {
        afFA[f][0] = *reinterpret_cast<const float4*>(Af + afo[f]);
        afFA[f][1] = *reinterpret_cast<const float4*>(Af + afo[f] + 4);
      }
      if (NS > 1) {
#pragma unroll
        for (int i = 0; i < 2; ++i) {
          wF[i][0] = *reinterpret_cast<const float4*>(Wf + wro[i] + BK);
          wF[i][1] = *reinterpret_cast<const float4*>(Wf + wro[i] + BK + 4);
        }
      }
    } else {
#pragma unroll
      for (int i = 0; i < 2; ++i)
        *reinterpret_cast<bf16x8*>(reinterpret_cast<char*>(lds_w) + (r4 + 128 * i) * 128 + stw) =
            *reinterpret_cast<const bf16x8*>(Wh + wro[i]);
#pragma unroll
      for (int f = 0; f < 4; ++f)
        afA[f] = *reinterpret_cast<const bf16x8*>(Ah + afo[f]);
      if (NS > 1) {
#pragma unroll
        for (int i = 0; i < 2; ++i)
          wH[i] = *reinterpret_cast<const bf16x8*>(Wh + wro[i] + BK);
      }
    }
    bar_lgkm();

    // ---- main K-loop: unroll-2, 1 lgkm-barrier per slab ----
    for (int s = 0; s < NS; s += 2) {
      // ===== even step: slab s (half 0), consume afA, prefetch afB(s+1) =====
      if (s + 1 < NS) {
        const int kf = (s + 1) * BK;
        if constexpr (CVT) {
#pragma unroll
          for (int f = 0; f < 4; ++f) {
            afFB[f][0] = *reinterpret_cast<const float4*>(Af + afo[f] + kf);
            afFB[f][1] = *reinterpret_cast<const float4*>(Af + afo[f] + kf + 4);
          }
        } else {
#pragma unroll
          for (int f = 0; f < 4; ++f)
            afB[f] = *reinterpret_cast<const bf16x8*>(Ah + afo[f] + kf);
        }
      }
      {
        bf16x8 av[4];
#pragma unroll
        for (int f = 0; f < 4; ++f) {
          if constexpr (CVT) av[f] = cvt8(afFA[f][0], afFA[f][1]);
          else               av[f] = afA[f];
        }
        __builtin_amdgcn_s_setprio(1);
#pragma unroll
        for (int fn = 0; fn < 4; ++fn) {
          bf16x8 wfr = *reinterpret_cast<const bf16x8*>(
              reinterpret_cast<const char*>(lds_w) + woff0 + fn * 2048);
#pragma unroll
          for (int fm = 0; fm < 4; ++fm)
            acc[fm][fn] = __builtin_amdgcn_mfma_f32_16x16x32_bf16(
                av[fm], wfr, acc[fm][fn], 0, 0, 0);
        }
        __builtin_amdgcn_s_setprio(0);
      }
      if (s + 1 < NS) {
        // stage W slab s+1 -> half 1
        if constexpr (CVT) {
#pragma unroll
          for (int i = 0; i < 2; ++i)
            *reinterpret_cast<bf16x8*>(
                reinterpret_cast<char*>(lds_w) + (((r4 + 128 * i) * 128 + stw) ^ 64)) =
                cvt8(wF[i][0], wF[i][1]);
          if (s + 2 < NS) {
            const int kf = (s + 2) * BK;
#pragma unroll
            for (int i = 0; i < 2; ++i) {
              wF[i][0] = *reinterpret_cast<const float4*>(Wf + wro[i] + kf);
              wF[i][1] = *reinterpret_cast<const float4*>(Wf + wro[i] + kf + 4);
            }
          }
        } else {
#pragma unroll
          for (int i = 0; i < 2; ++i)
            *reinterpret_cast<bf16x8*>(
                reinterpret_cast<char*>(lds_w) + (((r4 + 128 * i) * 128 + stw) ^ 64)) = wH[i];
          if (s + 2 < NS) {
            const int kf = (s + 2) * BK;
#pragma unroll
            for (int i = 0; i < 2; ++i)
              wH[i] = *reinterpret_cast<const bf16x8*>(Wh + wro[i] + kf);
          }
        }
      }
      bar_lgkm();

      // ===== odd step: slab s+1 (half 1), consume afB, prefetch afA(s+2) =====
      if (s + 1 < NS) {
        if (s + 2 < NS) {
          const int kf = (s + 2) * BK;
          if constexpr (CVT) {
#pragma unroll
            for (int f = 0; f < 4; ++f) {
              afFA[f][0] = *reinterpret_cast<const float4*>(Af + afo[f] + kf);
              afFA[f][1] = *reinterpret_cast<const float4*>(Af + afo[f] + kf + 4);
            }
          } else {
#pragma unroll
            for (int f = 0; f < 4; ++f)
              afA[f] = *reinterpret_cast<const bf16x8*>(Ah + afo[f] + kf);
          }
        }
        {
          bf16x8 av[4];
#pragma unroll
          for (int f = 0; f < 4; ++f) {
            if constexpr (CVT) av[f] = cvt8(afFB[f][0], afFB[f][1]);
            else               av[f] = afB[f];
          }
          __builtin_amdgcn_s_setprio(1);
#pragma unroll
          for (int fn = 0; fn < 4; ++fn) {
            bf16x8 wfr = *reinterpret_cast<const bf16x8*>(
                reinterpret_cast<const char*>(lds_w) + (woff0 ^ 64) + fn * 2048);
#pragma unroll
            for (int fm = 0; fm < 4; ++fm)
              acc[fm][fn] = __builtin_amdgcn_mfma_f32_16x16x32_bf16(
                  av[fm], wfr, acc[fm][fn], 0, 0, 0);
          }
          __builtin_amdgcn_s_setprio(0);
        }
        if (s + 2 < NS) {
          // stage W slab s+2 -> half 0
          if constexpr (CVT) {
#pragma unroll
            for (int i = 0; i < 2; ++i)
              *reinterpret_cast<bf16x8*>(
                  reinterpret_cast<char*>(lds_w) + (r4 + 128 * i) * 128 + stw) =
                  cvt8(wF[i][0], wF[i][1]);
            if (s + 3 < NS) {
              const int kf = (s + 3) * BK;
#pragma unroll
              for (int i = 0; i < 2; ++i) {
                wF[i][0] = *reinterpret_cast<const float4*>(Wf + wro[i] + kf);
                wF[i][1] = *reinterpret_cast<const float4*>(Wf + wro[i] + kf + 4);
              }
            }
          } else {
#pragma unroll
            for (int i = 0; i < 2; ++i)
              *reinterpret_cast<bf16x8*>(
                  reinterpret_cast<char*>(lds_w) + (r4 + 128 * i) * 128 + stw) = wH[i];
            if (s + 3 < NS) {
              const int kf = (s + 3) * BK;
#pragma unroll
              for (int i = 0; i < 2; ++i)
                wH[i] = *reinterpret_cast<const bf16x8*>(Wh + wro[i] + kf);
            }
          }
        }
        bar_lgkm();
      }
    }

    // ---- fused epilogue: per-row reduction over this 256-col sub-tile ----
    // C/D layout: col = lane&15, row = (lane>>4)*4 + reg  [verified m89/m91]
    // Max-first; ref blocks skip argmax + logit-sum (uniform branch).
#pragma unroll
    for (int fm = 0; fm < 4; ++fm) {
#pragma unroll
      for (int reg = 0; reg < 4; ++reg) {
        float lm = -INFINITY;
#pragma unroll
        for (int fn = 0; fn < 4; ++fn) {
          if (FULL || v0 + wn * 64 + fn * 16 + l15 < V)
            lm = fmaxf(lm, acc[fm][fn][reg]);
        }
#pragma unroll
        for (int d = 1; d < 16; d <<= 1) lm = fmaxf(lm, __shfl_xor(lm, d));
        // lm == exact row max (within this wave's 64-col tile)
        float se = 0.f, sm = 0.f; int li = 0x7fffffff;
#pragma unroll
        for (int fn = 0; fn < 4; ++fn) {
          const int v = v0 + wn * 64 + fn * 16 + l15;
          if (FULL || v < V) {
            const float x = acc[fm][fn][reg];
            se += __expf(x - lm);
            if (isPol) {
              sm += x;
              if (x == lm) li = min(li, v);
            }
          }
        }
        if (isPol) {
#pragma unroll
          for (int d = 1; d < 16; d <<= 1) {
            se += __shfl_xor(se, d);
            sm += __shfl_xor(sm, d);
            li  = min(li, __shfl_xor(li, d));
          }
        } else {
#pragma unroll
          for (int d = 1; d < 16; d <<= 1) se += __shfl_xor(se, d);
        }
        if (l15 == 0) {
          const int row = wm * 64 + fm * 16 + q * 4 + reg;
          lds_red[row * 4 + wn] = make_float4(lm, se, sm, __int_as_float(li));
        }
      }
    }
    __syncthreads();

    if (tid < BM) {
      float4 p0 = lds_red[tid * 4];
      float m = p0.x, se = p0.y, sm = p0.z; int idx = __float_as_int(p0.w);
#pragma unroll
      for (int j = 1; j < 4; ++j) {
        const float4 t = lds_red[tid * 4 + j];
        const int ti = __float_as_int(t.w);
        const float nm = fmaxf(m, t.x);
        se = se * sexp_fast(m - nm) + t.y * sexp_fast(t.x - nm);
        if (isPol) {
          sm += t.z;
          if (t.x > m || (t.x == m && ti < idx)) idx = ti;
        }
        m = nm;
      }
      const float nm = fmaxf(rm, m);
      rse = rse * sexp_fast(rm - nm) + se * sexp_fast(m - nm);
      if (isPol) {
        rsum += sm;
        if (m > rm || (m == rm && idx < ridx)) ridx = idx;
      }
      rm = nm;
    }
    __syncthreads();  // lds_red / lds_w free for next sub
  }

  if (tid < BM) {
    const int row = row0 + tid;
    if (row < M) {
      if (isPol) {
        reinterpret_cast<float4*>(partP)[(size_t)row * NC + chunk] =
            make_float4(rm, rse, rsum, __int_as_float(ridx));
      } else {
        reinterpret_cast<float2*>(partR)[(size_t)row * NC + chunk] =
            make_float2(rm, rse);
      }
    }
  }
}

// ---------------------------------------------------------------------------
// Kernel 2: per-row combine of chunk partials + gathered ref dot (f32 exact).
// Writes rowtab[row] = {tok_lp, kl, mean_v(log_probs_row), 0}
// grid = (M), block = 256
// ---------------------------------------------------------------------------
__global__ __launch_bounds__(256)
void combine_kernel(const float4* __restrict__ partP,
                    const float2* __restrict__ partR,
                    const float* __restrict__ refA,
                    const float* __restrict__ refW,
                    float4* __restrict__ rowtab,
                    int M, int K, int V, int NC)
{
  const int row = blockIdx.x;
  const int tid = threadIdx.x;

  __shared__ float redf[256];
  __shared__ int   redi[256];
  __shared__ float s_M, s_SE, s_SUM, s_Mr, s_SEr, s_dot;
  __shared__ int   s_idx;

  float m = -INFINITY, se = 0.f, sm = 0.f; int idx = 0x7fffffff;
  for (int i = tid; i < NC; i += 256) {
    float4 p = partP[(size_t)row * NC + i];
    int pi = __float_as_int(p.w);
    float nm = fmaxf(m, p.x);
    se = se * sexp(m - nm) + p.y * sexp(p.x - nm);
    if (p.x > m || (p.x == m && pi < idx)) idx = pi;
    m = nm;
    sm += p.z;
  }
  redf[tid] = m; redi[tid] = idx;
  __syncthreads();
  for (int s = 128; s > 0; s >>= 1) {
    if (tid < s) {
      float om = redf[tid + s]; int oi = redi[tid + s];
      if (om > redf[tid] || (om == redf[tid] && oi < redi[tid])) { redf[tid] = om; redi[tid] = oi; }
    }
    __syncthreads();
  }
  if (tid == 0) { s_M = redf[0]; s_idx = redi[0]; }
  __syncthreads();
  const float Mp = s_M; const int chosen = s_idx;

  float contrib = se * sexp(m - Mp);
  __syncthreads();
  redf[tid] = contrib; __syncthreads();
  for (int s = 128; s > 0; s >>= 1) { if (tid < s) redf[tid] += redf[tid + s]; __syncthreads(); }
  if (tid == 0) s_SE = redf[0];
  __syncthreads();
  redf[tid] = sm; __syncthreads();
  for (int s = 128; s > 0; s >>= 1) { if (tid < s) redf[tid] += redf[tid + s]; __syncthreads(); }
  if (tid == 0) s_SUM = redf[0];
  __syncthreads();

  float mr = -INFINITY, ser = 0.f;
  for (int i = tid; i < NC; i += 256) {
    float2 p = partR[(size_t)row * NC + i];
    float nm = fmaxf(mr, p.x);
    ser = ser * sexp(mr - nm) + p.y * sexp(p.x - nm);
    mr = nm;
  }
  redf[tid] = mr; __syncthreads();
  for (int s = 128; s > 0; s >>= 1) { if (tid < s) redf[tid] = fmaxf(redf[tid], redf[tid + s]); __syncthreads(); }
  if (tid == 0) s_Mr = redf[0];
  __syncthreads();
  const float Mr = s_Mr;
  float contribr = ser * sexp(mr - Mr);
  __syncthreads();
  redf[tid] = contribr; __syncthreads();
  for (int s = 128; s > 0; s >>= 1) { if (tid < s) redf[tid] += redf[tid + s]; __syncthreads(); }
  if (tid == 0) s_SEr = redf[0];
  __syncthreads();

  float dp = 0.f;
  const float* ar = refA + (size_t)row * K;
  const float* wr = refW + (size_t)chosen * K;
  for (int j = tid * 4; j < K; j += 256 * 4) {
    float4 x = *reinterpret_cast<const float4*>(ar + j);
    float4 y = *reinterpret_cast<const float4*>(wr + j);
    dp = fmaf(x.x, y.x, dp);
    dp = fmaf(x.y, y.y, dp);
    dp = fmaf(x.z, y.z, dp);
    dp = fmaf(x.w, y.w, dp);
  }
  __syncthreads();
  redf[tid] = dp; __syncthreads();
  for (int s = 128; s > 0; s >>= 1) { if (tid < s) redf[tid] += redf[tid + s]; __syncthreads(); }
  if (tid == 0) s_dot = redf[0];
  __syncthreads();

  if (tid == 0) {
    float lse     = Mp + logf(s_SE);
    float tok     = Mp - lse;
    float ref_lse = Mr + logf(s_SEr);
    float ref_tok = s_dot - ref_lse;
    float d  = ref_tok - tok;
    float kl = expm1f(d) - d;
    float rm3 = s_SUM / (float)V - lse;
    rowtab[row] = make_float4(tok, kl, rm3, 0.f);
  }
}

// ---------------------------------------------------------------------------
// Kernel 3: final reduction over rows -> 5 scalar outputs. grid=(1), block=256
// ---------------------------------------------------------------------------
__global__ __launch_bounds__(256)
void final_kernel(const float4* __restrict__ rowtab,
                  const float* __restrict__ mask,
                  const float* __restrict__ rewards,
                  float* __restrict__ out,
                  int M, int B, int T)
{
  const int tid = threadIdx.x;
  __shared__ float redf[256];
  __shared__ float s_mean, s_m3, s_var;
  __shared__ float s_kl[16], s_cnt[16];

  float st = 0.f, sm3 = 0.f;
  for (int r = tid; r < M; r += 256) {
    float4 v = rowtab[r];
    st += v.x; sm3 += v.z;
  }
  redf[tid] = st; __syncthreads();
  for (int s = 128; s > 0; s >>= 1) { if (tid < s) redf[tid] += redf[tid + s]; __syncthreads(); }
  if (tid == 0) s_mean = redf[0] / (float)M;
  __syncthreads();
  redf[tid] = sm3; __syncthreads();
  for (int s = 128; s > 0; s >>= 1) { if (tid < s) redf[tid] += redf[tid + s]; __syncthreads(); }
  if (tid == 0) s_m3 = redf[0] / (float)M;
  __syncthreads();

  const float mean = s_mean;
  float sv = 0.f;
  for (int r = tid; r < M; r += 256) { float d = rowtab[r].x - mean; sv = fmaf(d, d, sv); }
  __syncthreads();
  redf[tid] = sv; __syncthreads();
  for (int s = 128; s > 0; s >>= 1) { if (tid < s) redf[tid] += redf[tid + s]; __syncthreads(); }
  if (tid == 0) s_var = redf[0];
  __syncthreads();

  const int nb = B < 16 ? B : 16;
  for (int b = 0; b < nb; ++b) {
    float lk = 0.f, lc = 0.f;
    for (int t = tid; t < T; t += 256) {
      int r = b * T + t;
      float mk = mask[r];
      lk = fmaf(rowtab[r].y, mk, lk);
      lc += mk;
    }
    __syncthreads();
    redf[tid] = lk; __syncthreads();
    for (int s = 128; s > 0; s >>= 1) { if (tid < s) redf[tid] += redf[tid + s]; __syncthreads(); }
    if (tid == 0) s_kl[b] = redf[0];
    __syncthreads();
    redf[tid] = lc; __syncthreads();
    for (int s = 128; s > 0; s >>= 1) { if (tid < s) redf[tid] += redf[tid + s]; __syncthreads(); }
    if (tid == 0) s_cnt[b] = redf[0];
    __syncthreads();
  }

  if (tid == 0) {
    float rmean = 0.f;
    for (int b = 0; b < B; ++b) rmean += rewards[b];
    rmean /= (float)B;
    float rv = 0.f;
    for (int b = 0; b < B; ++b) { float d = rewards[b] - rmean; rv += d * d; }
    float rstd = sqrtf(rv / (float)(B > 1 ? B - 1 : 1));

    float loss = 0.f, m4n = 0.f, m4d = 0.f;
    for (int b = 0; b < nb; ++b) {
      float adv  = (rewards[b] - rmean) / (rstd + 1e-8f);
      float cnt  = s_cnt[b];
      float seql = fmaxf(cnt, 1.0f);
      loss += (-adv * cnt + GRPO_BETA * s_kl[b]) / seql;
      m4n += s_kl[b];
      m4d += cnt;
    }
    loss /= (float)B;

    out[0] = loss;
    out[1] = s_mean;
    out[2] = sqrtf(s_var / (float)(M - 1));
    out[3] = s_m3;
    out[4] = m4n / m4d;
  }
}

// ---------------------------------------------------------------------------
extern "C" void kernel_launch(void* const* d_in, const int* in_sizes, int n_in,
                              void* d_out, int out_size, void* d_ws, size_t ws_size,
                              hipStream_t stream)
{
  if (n_in < 6) return;
  const float* A       = (const float*)d_in[0];
  const float* W       = (const float*)d_in[1];
  const float* mask    = (const float*)d_in[2];
  const float* rewards = (const float*)d_in[3];
  const float* rA      = (const float*)d_in[4];
  const float* rW      = (const float*)d_in[5];

  const int M = in_sizes[2];            // B*T
  const int B = in_sizes[3];
  const int T = M / B;
  const int K = in_sizes[0] / M;        // H
  const int V = in_sizes[1] / K;

  const int gx = (M + BM - 1) / BM;
  const bool full = (V % BN) == 0;

  // ---- workspace budgeting ----
  const size_t aBytes = (size_t)M * K * sizeof(__bf16);
  const size_t wBytes = (size_t)V * K * sizeof(__bf16);
  auto partBytes = [&](int nl) -> size_t {
    int nc = (V + BN * nl - 1) / (BN * nl);
    return (size_t)M * nc * 16 + (size_t)M * nc * 8 + (size_t)M * 16;
  };

  int NL = 1;
  bool canPrep = false;
  if (K % 8 == 0) {
    for (int nl = 1; nl <= 1024; nl <<= 1) {
      size_t pb = (partBytes(nl) + 255) & ~(size_t)255;
      if (pb + 2 * aBytes + 2 * wBytes <= ws_size) { NL = nl; canPrep = true; break; }
    }
  }
  if (!canPrep) {
    NL = 1;
    while (partBytes(NL) > ws_size && NL < 1024) NL <<= 1;
  }
  const int NC = (V + BN * NL - 1) / (BN * NL);

  float* partP  = (float*)d_ws;                    // M*NC float4
  float* partR  = partP + (size_t)M * NC * 4;      // M*NC float2
  float* rowtab = partR + (size_t)M * NC * 2;      // M float4

  dim3 g1(2 * gx * NC), b1(512);

  if (canPrep) {
    size_t pb = (partBytes(NL) + 255) & ~(size_t)255;
    __bf16* Ab  = (__bf16*)((char*)d_ws + pb);
    __bf16* rAb = Ab  + (size_t)M * K;
    __bf16* Wb  = rAb + (size_t)M * K;
    __bf16* rWb = Wb  + (size_t)V * K;

    const long long nA8 = (long long)M * K / 8;
    const long long nW8 = (long long)V * K / 8;
    cvt_bf16_kernel<<<dim3(512),  dim3(256), 0, stream>>>(A,  Ab,  nA8);
    cvt_bf16_kernel<<<dim3(512),  dim3(256), 0, stream>>>(rA, rAb, nA8);
    cvt_bf16_kernel<<<dim3(2048), dim3(256), 0, stream>>>(W,  Wb,  nW8);
    cvt_bf16_kernel<<<dim3(2048), dim3(256), 0, stream>>>(rW, rWb, nW8);

    if (full) {
      fused_gemm_reduce<false, true ><<<g1, b1, 0, stream>>>(
          nullptr, nullptr, nullptr, nullptr, Ab, Wb, rAb, rWb,
          partP, partR, M, K, V, NC, NL, gx);
    } else {
      fused_gemm_reduce<false, false><<<g1, b1, 0, stream>>>(
          nullptr, nullptr, nullptr, nullptr, Ab, Wb, rAb, rWb,
          partP, partR, M, K, V, NC, NL, gx);
    }
  } else {
    if (full) {
      fused_gemm_reduce<true , true ><<<g1, b1, 0, stream>>>(
          A, W, rA, rW, nullptr, nullptr, nullptr, nullptr,
          partP, partR, M, K, V, NC, NL, gx);
    } else {
      fused_gemm_reduce<true , false><<<g1, b1, 0, stream>>>(
          A, W, rA, rW, nullptr, nullptr, nullptr, nullptr,
          partP, partR, M, K, V, NC, NL, gx);
    }
  }

  combine_kernel<<<dim3(M), dim3(256), 0, stream>>>(
      (const float4*)partP, (const float2*)partR, rA, rW, (float4*)rowtab, M, K, V, NC);
  final_kernel<<<dim3(1), dim3(256), 0, stream>>>(
      (const float4*)rowtab, mask, rewards, (float*)d_out, M, B, T);
}

// Round 12
// 1348.070 us; speedup vs baseline: 1.0227x; 1.0227x over previous
//
#include <hip/hip_runtime.h>
#include <math.h>

#define GRPO_BETA 0.1f

constexpr int BM = 128;    // rows per block tile
constexpr int BN = 256;    // vocab cols per block tile (chunk width)
constexpr int BK = 32;     // k-slab; LDS W rows hold 2 slabs (128B, dbuf by bit6)

typedef __attribute__((ext_vector_type(4))) float   f32x4;
typedef __attribute__((ext_vector_type(8))) __bf16  bf16x8;

// NaN-safe exp for lse merges: args expected <= 0; fminf(NaN,0)=0.
__device__ __forceinline__ float sexp_fast(float a) { return __expf(fminf(a, 0.f)); }
__device__ __forceinline__ float sexp(float a)      { return expf(fminf(a, 0.f)); }

__device__ __forceinline__ bf16x8 cvt8(float4 a, float4 b) {
  bf16x8 r;
  r[0] = (__bf16)a.x; r[1] = (__bf16)a.y; r[2] = (__bf16)a.z; r[3] = (__bf16)a.w;
  r[4] = (__bf16)b.x; r[5] = (__bf16)b.y; r[6] = (__bf16)b.z; r[7] = (__bf16)b.w;
  return r;
}

// barrier WITHOUT vmcnt drain: LDS writes made visible (lgkmcnt), global
// prefetch loads stay in flight across the barrier (T4-minimum).
__device__ __forceinline__ void bar_lgkm() {
  asm volatile("s_waitcnt lgkmcnt(0)\n\ts_barrier" ::: "memory");
}

// ---------------------------------------------------------------------------
// Kernel 0: f32 -> bf16 conversion (grid-stride, 16B loads x2 -> 16B store).
// ---------------------------------------------------------------------------
__global__ __launch_bounds__(256)
void cvt_bf16_kernel(const float* __restrict__ src, __bf16* __restrict__ dst,
                     long long n8)
{
  long long i = (long long)blockIdx.x * blockDim.x + threadIdx.x;
  const long long stride = (long long)gridDim.x * blockDim.x;
  for (; i < n8; i += stride) {
    const float4 a = *reinterpret_cast<const float4*>(src + i * 8);
    const float4 b = *reinterpret_cast<const float4*>(src + i * 8 + 4);
    *reinterpret_cast<bf16x8*>(dst + i * 8) = cvt8(a, b);
  }
}

// ---------------------------------------------------------------------------
// Kernel 1: FUSED policy+ref bf16-MFMA GEMM (logits = A[M,K] x W[V,K]^T) with
// per-row per-256-col-chunk reductions.
// grid = 2*gx*NC; after XCD remap, block PARITY selects policy vs ref.
// A-fragments load DIRECTLY FROM GLOBAL (layout HW-verified in r11): the
// MFMA A-operand (row=lane&15, k=(lane>>4)*8+[0..8)) is 16B-contiguous per
// lane -> one dwordx4 per fragment; the per-step A slice (8 KB) is shared by
// 4 waves -> L1/L2-hit. SINGLE-buffered (r11's double buffer spilled 36 regs
// -> 234 MB scratch traffic; this version's register delta vs r10 is ~0).
// LDS holds W only: rows 128B = 2 k-slabs (parity bit 6), XOR swizzle
// byte x of row r at r*128 + (x ^ ((r&7)<<4)); 16B-granule staging writes.
// Per-block-step LDS traffic 88 KB -> 48 KB vs r10.
// Pipeline per K-step s (ONE lgkm-barrier per step):
//   load A-frags(s) direct | MFMA(half s&1) | stage W regs(s+1) -> other
//   half | issue W loads (s+2) | bar.  Global loads ride across the barrier.
// CVT=true: f32 inputs, convert in-flight (fallback). FULL: V % BN == 0.
// ---------------------------------------------------------------------------
template <bool CVT, bool FULL>
__global__ __launch_bounds__(512, 4)
void fused_gemm_reduce(const float* __restrict__ AfP, const float* __restrict__ WfP,
                       const float* __restrict__ AfR, const float* __restrict__ WfR,
                       const __bf16* __restrict__ AhP, const __bf16* __restrict__ WhP,
                       const __bf16* __restrict__ AhR, const __bf16* __restrict__ WhR,
                       float* __restrict__ partP, float* __restrict__ partR,
                       int M, int K, int V, int NC, int NL, int gx)
{
  __shared__ __align__(16) unsigned short lds_w[BN * 64];   // 32 KB (2 slabs)
  __shared__ __align__(16) float4 lds_red[BM * 4];          // 8 KB

  const int tid  = threadIdx.x;
  const int lane = tid & 63;
  const int wave = tid >> 6;      // 0..7
  const int wm   = wave >> 2;     // 0..1  (M half)
  const int wn   = wave & 3;      // 0..3  (N quarter)
  const int l15  = lane & 15;
  const int q    = lane >> 4;     // 0..3

  // ---- XCD-aware block remap (bijective when nb % 8 == 0) + parity split ----
  const int nb  = gridDim.x;
  int wl = blockIdx.x;
  if ((nb & 7) == 0) wl = (wl & 7) * (nb >> 3) + (wl >> 3);
  const bool isPol = (wl & 1) == 0;     // even -> policy, odd -> ref
  const int  w2    = wl >> 1;
  const int  bx    = w2 % gx;
  const int  chunk = w2 / gx;
  const int  row0  = bx * BM;

  // uniform input selects
  const float*  Af = isPol ? AfP : AfR;
  const float*  Wf = isPol ? WfP : WfR;
  const __bf16* Ah = isPol ? AhP : AhR;
  const __bf16* Wh = isPol ? WhP : WhR;

  // ---- W staging map: lane covers 8 k-elems (16B granule) of one row ----
  const int t3 = tid & 3;
  const int r4 = tid >> 2;        // 0..127
  const int stw = ((t3 * 16) ^ ((r4 & 7) << 4));

  // ---- A-fragment global element offsets (frag f, k-slab 0) ----
  int afo[4];
#pragma unroll
  for (int f = 0; f < 4; ++f)
    afo[f] = min(row0 + wm * 64 + f * 16 + l15, M - 1) * K + q * 8;

  // ---- W fragment LDS byte offsets (slab parity = bit 6; frag fn adds 2048) ----
  const int swzr  = ((q * 16) ^ ((l15 & 7) << 4));
  const int woff0 = (wn * 64 + l15) * 128 + swzr;

  // running per-row records (threads 0..127 own local row = tid)
  float rm = -INFINITY, rse = 0.f, rsum = 0.f;
  int   ridx = 0x7fffffff;

  const int NS = K / BK;

  for (int sub = 0; sub < NL; ++sub) {
    const int v0 = (chunk * NL + sub) * BN;
    if (v0 >= V) break;

    int wro[2];
#pragma unroll
    for (int i = 0; i < 2; ++i)
      wro[i] = min(v0 + r4 + 128 * i, V - 1) * K + t3 * 8;

    f32x4 acc[4][4];
#pragma unroll
    for (int i = 0; i < 4; ++i)
#pragma unroll
      for (int j = 0; j < 4; ++j) acc[i][j] = (f32x4){0.f, 0.f, 0.f, 0.f};

    // W prefetch registers (one slab)
    bf16x8 wH[2];               // bf16 path
    float4 wF[2][2];            // f32 path

    // ---- prologue: W slab0 -> LDS half0; W slab1 -> regs ----
    if constexpr (CVT) {
#pragma unroll
      for (int i = 0; i < 2; ++i) {
        const float4 w0 = *reinterpret_cast<const float4*>(Wf + wro[i]);
        const float4 w1 = *reinterpret_cast<const float4*>(Wf + wro[i] + 4);
        *reinterpret_cast<bf16x8*>(reinterpret_cast<char*>(lds_w) + (r4 + 128 * i) * 128 + stw) =
            cvt8(w0, w1);
      }
      if (NS > 1) {
#pragma unroll
        for (int i = 0; i < 2; ++i) {
          wF[i][0] = *reinterpret_cast<const float4*>(Wf + wro[i] + BK);
          wF[i][1] = *reinterpret_cast<const float4*>(Wf + wro[i] + BK + 4);
        }
      }
    } else {
#pragma unroll
      for (int i = 0; i < 2; ++i)
        *reinterpret_cast<bf16x8*>(reinterpret_cast<char*>(lds_w) + (r4 + 128 * i) * 128 + stw) =
            *reinterpret_cast<const bf16x8*>(Wh + wro[i]);
      if (NS > 1) {
#pragma unroll
        for (int i = 0; i < 2; ++i)
          wH[i] = *reinterpret_cast<const bf16x8*>(Wh + wro[i] + BK);
      }
    }
    bar_lgkm();

    // ---- main K-loop: 1 lgkm-barrier per slab ----
    for (int s = 0; s < NS; ++s) {
      const int p = (s & 1) << 6;     // LDS half of slab s
      const int ks = s * BK;

      // A-fragments for slab s: direct from global (L1/L2-hit), single buffer
      bf16x8 av[4];
      if constexpr (CVT) {
#pragma unroll
        for (int f = 0; f < 4; ++f) {
          const float4 a0 = *reinterpret_cast<const float4*>(Af + afo[f] + ks);
          const float4 a1 = *reinterpret_cast<const float4*>(Af + afo[f] + ks + 4);
          av[f] = cvt8(a0, a1);
        }
      } else {
#pragma unroll
        for (int f = 0; f < 4; ++f)
          av[f] = *reinterpret_cast<const bf16x8*>(Ah + afo[f] + ks);
      }

      __builtin_amdgcn_s_setprio(1);
#pragma unroll
      for (int fn = 0; fn < 4; ++fn) {
        bf16x8 wfr = *reinterpret_cast<const bf16x8*>(
            reinterpret_cast<const char*>(lds_w) + (woff0 ^ p) + fn * 2048);
#pragma unroll
        for (int fm = 0; fm < 4; ++fm)
          acc[fm][fn] = __builtin_amdgcn_mfma_f32_16x16x32_bf16(
              av[fm], wfr, acc[fm][fn], 0, 0, 0);
      }
      __builtin_amdgcn_s_setprio(0);

      if (s + 1 < NS) {
        const int p1 = ((s + 1) & 1) << 6;   // stage W slab s+1 into other half
        if constexpr (CVT) {
#pragma unroll
          for (int i = 0; i < 2; ++i)
            *reinterpret_cast<bf16x8*>(
                reinterpret_cast<char*>(lds_w) + (((r4 + 128 * i) * 128 + stw) ^ p1)) =
                cvt8(wF[i][0], wF[i][1]);
          if (s + 2 < NS) {
            const int kf = (s + 2) * BK;
#pragma unroll
            for (int i = 0; i < 2; ++i) {
              wF[i][0] = *reinterpret_cast<const float4*>(Wf + wro[i] + kf);
              wF[i][1] = *reinterpret_cast<const float4*>(Wf + wro[i] + kf + 4);
            }
          }
        } else {
#pragma unroll
          for (int i = 0; i < 2; ++i)
            *reinterpret_cast<bf16x8*>(
                reinterpret_cast<char*>(lds_w) + (((r4 + 128 * i) * 128 + stw) ^ p1)) = wH[i];
          if (s + 2 < NS) {
            const int kf = (s + 2) * BK;
#pragma unroll
            for (int i = 0; i < 2; ++i)
              wH[i] = *reinterpret_cast<const bf16x8*>(Wh + wro[i] + kf);
          }
        }
      }
      bar_lgkm();
    }

    // ---- fused epilogue: per-row reduction over this 256-col sub-tile ----
    // C/D layout: col = lane&15, row = (lane>>4)*4 + reg  [verified m89/m91]
    // Max-first; ref blocks skip argmax + logit-sum (uniform branch).
#pragma unroll
    for (int fm = 0; fm < 4; ++fm) {
#pragma unroll
      for (int reg = 0; reg < 4; ++reg) {
        float lm = -INFINITY;
#pragma unroll
        for (int fn = 0; fn < 4; ++fn) {
          if (FULL || v0 + wn * 64 + fn * 16 + l15 < V)
            lm = fmaxf(lm, acc[fm][fn][reg]);
        }
#pragma unroll
        for (int d = 1; d < 16; d <<= 1) lm = fmaxf(lm, __shfl_xor(lm, d));
        // lm == exact row max (within this wave's 64-col tile)
        float se = 0.f, sm = 0.f; int li = 0x7fffffff;
#pragma unroll
        for (int fn = 0; fn < 4; ++fn) {
          const int v = v0 + wn * 64 + fn * 16 + l15;
          if (FULL || v < V) {
            const float x = acc[fm][fn][reg];
            se += __expf(x - lm);
            if (isPol) {
              sm += x;
              if (x == lm) li = min(li, v);
            }
          }
        }
        if (isPol) {
#pragma unroll
          for (int d = 1; d < 16; d <<= 1) {
            se += __shfl_xor(se, d);
            sm += __shfl_xor(sm, d);
            li  = min(li, __shfl_xor(li, d));
          }
        } else {
#pragma unroll
          for (int d = 1; d < 16; d <<= 1) se += __shfl_xor(se, d);
        }
        if (l15 == 0) {
          const int row = wm * 64 + fm * 16 + q * 4 + reg;
          lds_red[row * 4 + wn] = make_float4(lm, se, sm, __int_as_float(li));
        }
      }
    }
    __syncthreads();

    if (tid < BM) {
      float4 p0 = lds_red[tid * 4];
      float m = p0.x, se = p0.y, sm = p0.z; int idx = __float_as_int(p0.w);
#pragma unroll
      for (int j = 1; j < 4; ++j) {
        const float4 t = lds_red[tid * 4 + j];
        const int ti = __float_as_int(t.w);
        const float nm = fmaxf(m, t.x);
        se = se * sexp_fast(m - nm) + t.y * sexp_fast(t.x - nm);
        if (isPol) {
          sm += t.z;
          if (t.x > m || (t.x == m && ti < idx)) idx = ti;
        }
        m = nm;
      }
      const float nm = fmaxf(rm, m);
      rse = rse * sexp_fast(rm - nm) + se * sexp_fast(m - nm);
      if (isPol) {
        rsum += sm;
        if (m > rm || (m == rm && idx < ridx)) ridx = idx;
      }
      rm = nm;
    }
    __syncthreads();  // lds_red / lds_w free for next sub
  }

  if (tid < BM) {
    const int row = row0 + tid;
    if (row < M) {
      if (isPol) {
        reinterpret_cast<float4*>(partP)[(size_t)row * NC + chunk] =
            make_float4(rm, rse, rsum, __int_as_float(ridx));
      } else {
        reinterpret_cast<float2*>(partR)[(size_t)row * NC + chunk] =
            make_float2(rm, rse);
      }
    }
  }
}

// ---------------------------------------------------------------------------
// Kernel 2: per-row combine of chunk partials + gathered ref dot (f32 exact).
// Writes rowtab[row] = {tok_lp, kl, mean_v(log_probs_row), 0}
// grid = (M), block = 256
// ---------------------------------------------------------------------------
__global__ __launch_bounds__(256)
void combine_kernel(const float4* __restrict__ partP,
                    const float2* __restrict__ partR,
                    const float* __restrict__ refA,
                    const float* __restrict__ refW,
                    float4* __restrict__ rowtab,
                    int M, int K, int V, int NC)
{
  const int row = blockIdx.x;
  const int tid = threadIdx.x;

  __shared__ float redf[256];
  __shared__ int   redi[256];
  __shared__ float s_M, s_SE, s_SUM, s_Mr, s_SEr, s_dot;
  __shared__ int   s_idx;

  float m = -INFINITY, se = 0.f, sm = 0.f; int idx = 0x7fffffff;
  for (int i = tid; i < NC; i += 256) {
    float4 p = partP[(size_t)row * NC + i];
    int pi = __float_as_int(p.w);
    float nm = fmaxf(m, p.x);
    se = se * sexp(m - nm) + p.y * sexp(p.x - nm);
    if (p.x > m || (p.x == m && pi < idx)) idx = pi;
    m = nm;
    sm += p.z;
  }
  redf[tid] = m; redi[tid] = idx;
  __syncthreads();
  for (int s = 128; s > 0; s >>= 1) {
    if (tid < s) {
      float om = redf[tid + s]; int oi = redi[tid + s];
      if (om > redf[tid] || (om == redf[tid] && oi < redi[tid])) { redf[tid] = om; redi[tid] = oi; }
    }
    __syncthreads();
  }
  if (tid == 0) { s_M = redf[0]; s_idx = redi[0]; }
  __syncthreads();
  const float Mp = s_M; const int chosen = s_idx;

  float contrib = se * sexp(m - Mp);
  __syncthreads();
  redf[tid] = contrib; __syncthreads();
  for (int s = 128; s > 0; s >>= 1) { if (tid < s) redf[tid] += redf[tid + s]; __syncthreads(); }
  if (tid == 0) s_SE = redf[0];
  __syncthreads();
  redf[tid] = sm; __syncthreads();
  for (int s = 128; s > 0; s >>= 1) { if (tid < s) redf[tid] += redf[tid + s]; __syncthreads(); }
  if (tid == 0) s_SUM = redf[0];
  __syncthreads();

  float mr = -INFINITY, ser = 0.f;
  for (int i = tid; i < NC; i += 256) {
    float2 p = partR[(size_t)row * NC + i];
    float nm = fmaxf(mr, p.x);
    ser = ser * sexp(mr - nm) + p.y * sexp(p.x - nm);
    mr = nm;
  }
  redf[tid] = mr; __syncthreads();
  for (int s = 128; s > 0; s >>= 1) { if (tid < s) redf[tid] = fmaxf(redf[tid], redf[tid + s]); __syncthreads(); }
  if (tid == 0) s_Mr = redf[0];
  __syncthreads();
  const float Mr = s_Mr;
  float contribr = ser * sexp(mr - Mr);
  __syncthreads();
  redf[tid] = contribr; __syncthreads();
  for (int s = 128; s > 0; s >>= 1) { if (tid < s) redf[tid] += redf[tid + s]; __syncthreads(); }
  if (tid == 0) s_SEr = redf[0];
  __syncthreads();

  float dp = 0.f;
  const float* ar = refA + (size_t)row * K;
  const float* wr = refW + (size_t)chosen * K;
  for (int j = tid * 4; j < K; j += 256 * 4) {
    float4 x = *reinterpret_cast<const float4*>(ar + j);
    float4 y = *reinterpret_cast<const float4*>(wr + j);
    dp = fmaf(x.x, y.x, dp);
    dp = fmaf(x.y, y.y, dp);
    dp = fmaf(x.z, y.z, dp);
    dp = fmaf(x.w, y.w, dp);
  }
  __syncthreads();
  redf[tid] = dp; __syncthreads();
  for (int s = 128; s > 0; s >>= 1) { if (tid < s) redf[tid] += redf[tid + s]; __syncthreads(); }
  if (tid == 0) s_dot = redf[0];
  __syncthreads();

  if (tid == 0) {
    float lse     = Mp + logf(s_SE);
    float tok     = Mp - lse;
    float ref_lse = Mr + logf(s_SEr);
    float ref_tok = s_dot - ref_lse;
    float d  = ref_tok - tok;
    float kl = expm1f(d) - d;
    float rm3 = s_SUM / (float)V - lse;
    rowtab[row] = make_float4(tok, kl, rm3, 0.f);
  }
}

// ---------------------------------------------------------------------------
// Kernel 3: final reduction over rows -> 5 scalar outputs. grid=(1), block=256
// ---------------------------------------------------------------------------
__global__ __launch_bounds__(256)
void final_kernel(const float4* __restrict__ rowtab,
                  const float* __restrict__ mask,
                  const float* __restrict__ rewards,
                  float* __restrict__ out,
                  int M, int B, int T)
{
  const int tid = threadIdx.x;
  __shared__ float redf[256];
  __shared__ float s_mean, s_m3, s_var;
  __shared__ float s_kl[16], s_cnt[16];

  float st = 0.f, sm3 = 0.f;
  for (int r = tid; r < M; r += 256) {
    float4 v = rowtab[r];
    st += v.x; sm3 += v.z;
  }
  redf[tid] = st; __syncthreads();
  for (int s = 128; s > 0; s >>= 1) { if (tid < s) redf[tid] += redf[tid + s]; __syncthreads(); }
  if (tid == 0) s_mean = redf[0] / (float)M;
  __syncthreads();
  redf[tid] = sm3; __syncthreads();
  for (int s = 128; s > 0; s >>= 1) { if (tid < s) redf[tid] += redf[tid + s]; __syncthreads(); }
  if (tid == 0) s_m3 = redf[0] / (float)M;
  __syncthreads();

  const float mean = s_mean;
  float sv = 0.f;
  for (int r = tid; r < M; r += 256) { float d = rowtab[r].x - mean; sv = fmaf(d, d, sv); }
  __syncthreads();
  redf[tid] = sv; __syncthreads();
  for (int s = 128; s > 0; s >>= 1) { if (tid < s) redf[tid] += redf[tid + s]; __syncthreads(); }
  if (tid == 0) s_var = redf[0];
  __syncthreads();

  const int nb = B < 16 ? B : 16;
  for (int b = 0; b < nb; ++b) {
    float lk = 0.f, lc = 0.f;
    for (int t = tid; t < T; t += 256) {
      int r = b * T + t;
      float mk = mask[r];
      lk = fmaf(rowtab[r].y, mk, lk);
      lc += mk;
    }
    __syncthreads();
    redf[tid] = lk; __syncthreads();
    for (int s = 128; s > 0; s >>= 1) { if (tid < s) redf[tid] += redf[tid + s]; __syncthreads(); }
    if (tid == 0) s_kl[b] = redf[0];
    __syncthreads();
    redf[tid] = lc; __syncthreads();
    for (int s = 128; s > 0; s >>= 1) { if (tid < s) redf[tid] += redf[tid + s]; __syncthreads(); }
    if (tid == 0) s_cnt[b] = redf[0];
    __syncthreads();
  }

  if (tid == 0) {
    float rmean = 0.f;
    for (int b = 0; b < B; ++b) rmean += rewards[b];
    rmean /= (float)B;
    float rv = 0.f;
    for (int b = 0; b < B; ++b) { float d = rewards[b] - rmean; rv += d * d; }
    float rstd = sqrtf(rv / (float)(B > 1 ? B - 1 : 1));

    float loss = 0.f, m4n = 0.f, m4d = 0.f;
    for (int b = 0; b < nb; ++b) {
      float adv  = (rewards[b] - rmean) / (rstd + 1e-8f);
      float cnt  = s_cnt[b];
      float seql = fmaxf(cnt, 1.0f);
      loss += (-adv * cnt + GRPO_BETA * s_kl[b]) / seql;
      m4n += s_kl[b];
      m4d += cnt;
    }
    loss /= (float)B;

    out[0] = loss;
    out[1] = s_mean;
    out[2] = sqrtf(s_var / (float)(M - 1));
    out[3] = s_m3;
    out[4] = m4n / m4d;
  }
}

// ---------------------------------------------------------------------------
extern "C" void kernel_launch(void* const* d_in, const int* in_sizes, int n_in,
                              void* d_out, int out_size, void* d_ws, size_t ws_size,
                              hipStream_t stream)
{
  if (n_in < 6) return;
  const float* A       = (const float*)d_in[0];
  const float* W       = (const float*)d_in[1];
  const float* mask    = (const float*)d_in[2];
  const float* rewards = (const float*)d_in[3];
  const float* rA      = (const float*)d_in[4];
  const float* rW      = (const float*)d_in[5];

  const int M = in_sizes[2];            // B*T
  const int B = in_sizes[3];
  const int T = M / B;
  const int K = in_sizes[0] / M;        // H
  const int V = in_sizes[1] / K;

  const int gx = (M + BM - 1) / BM;
  const bool full = (V % BN) == 0;

  // ---- workspace budgeting ----
  const size_t aBytes = (size_t)M * K * sizeof(__bf16);
  const size_t wBytes = (size_t)V * K * sizeof(__bf16);
  auto partBytes = [&](int nl) -> size_t {
    int nc = (V + BN * nl - 1) / (BN * nl);
    return (size_t)M * nc * 16 + (size_t)M * nc * 8 + (size_t)M * 16;
  };

  int NL = 1;
  bool canPrep = false;
  if (K % 8 == 0) {
    for (int nl = 1; nl <= 1024; nl <<= 1) {
      size_t pb = (partBytes(nl) + 255) & ~(size_t)255;
      if (pb + 2 * aBytes + 2 * wBytes <= ws_size) { NL = nl; canPrep = true; break; }
    }
  }
  if (!canPrep) {
    NL = 1;
    while (partBytes(NL) > ws_size && NL < 1024) NL <<= 1;
  }
  const int NC = (V + BN * NL - 1) / (BN * NL);

  float* partP  = (float*)d_ws;                    // M*NC float4
  float* partR  = partP + (size_t)M * NC * 4;      // M*NC float2
  float* rowtab = partR + (size_t)M * NC * 2;      // M float4

  dim3 g1(2 * gx * NC), b1(512);

  if (canPrep) {
    size_t pb = (partBytes(NL) + 255) & ~(size_t)255;
    __bf16* Ab  = (__bf16*)((char*)d_ws + pb);
    __bf16* rAb = Ab  + (size_t)M * K;
    __bf16* Wb  = rAb + (size_t)M * K;
    __bf16* rWb = Wb  + (size_t)V * K;

    const long long nA8 = (long long)M * K / 8;
    const long long nW8 = (long long)V * K / 8;
    cvt_bf16_kernel<<<dim3(512),  dim3(256), 0, stream>>>(A,  Ab,  nA8);
    cvt_bf16_kernel<<<dim3(512),  dim3(256), 0, stream>>>(rA, rAb, nA8);
    cvt_bf16_kernel<<<dim3(2048), dim3(256), 0, stream>>>(W,  Wb,  nW8);
    cvt_bf16_kernel<<<dim3(2048), dim3(256), 0, stream>>>(rW, rWb, nW8);

    if (full) {
      fused_gemm_reduce<false, true ><<<g1, b1, 0, stream>>>(
          nullptr, nullptr, nullptr, nullptr, Ab, Wb, rAb, rWb,
          partP, partR, M, K, V, NC, NL, gx);
    } else {
      fused_gemm_reduce<false, false><<<g1, b1, 0, stream>>>(
          nullptr, nullptr, nullptr, nullptr, Ab, Wb, rAb, rWb,
          partP, partR, M, K, V, NC, NL, gx);
    }
  } else {
    if (full) {
      fused_gemm_reduce<true , true ><<<g1, b1, 0, stream>>>(
          A, W, rA, rW, nullptr, nullptr, nullptr, nullptr,
          partP, partR, M, K, V, NC, NL, gx);
    } else {
      fused_gemm_reduce<true , false><<<g1, b1, 0, stream>>>(
          A, W, rA, rW, nullptr, nullptr, nullptr, nullptr,
          partP, partR, M, K, V, NC, NL, gx);
    }
  }

  combine_kernel<<<dim3(M), dim3(256), 0, stream>>>(
      (const float4*)partP, (const float2*)partR, rA, rW, (float4*)rowtab, M, K, V, NC);
  final_kernel<<<dim3(1), dim3(256), 0, stream>>>(
      (const float4*)rowtab, mask, rewards, (float*)d_out, M, B, T);
}

// Round 13
// 877.753 us; speedup vs baseline: 1.5707x; 1.5358x over previous
//
#include <hip/hip_runtime.h>
#include <math.h>

#define GRPO_BETA 0.1f

constexpr int BM = 128;    // rows per block tile
constexpr int BN = 256;    // vocab cols per block tile (chunk width)

typedef __attribute__((ext_vector_type(4))) float   f32x4;
typedef __attribute__((ext_vector_type(8))) __bf16  bf16x8;

// NaN-safe exp for lse merges: args expected <= 0; fminf(NaN,0)=0.
__device__ __forceinline__ float sexp_fast(float a) { return __expf(fminf(a, 0.f)); }
__device__ __forceinline__ float sexp(float a)      { return expf(fminf(a, 0.f)); }

__device__ __forceinline__ bf16x8 cvt8(float4 a, float4 b) {
  bf16x8 r;
  r[0] = (__bf16)a.x; r[1] = (__bf16)a.y; r[2] = (__bf16)a.z; r[3] = (__bf16)a.w;
  r[4] = (__bf16)b.x; r[5] = (__bf16)b.y; r[6] = (__bf16)b.z; r[7] = (__bf16)b.w;
  return r;
}

// barrier WITHOUT vmcnt drain (CVT fallback path only).
__device__ __forceinline__ void bar_lgkm() {
  asm volatile("s_waitcnt lgkmcnt(0)\n\ts_barrier" ::: "memory");
}

// async global->LDS DMA, 16B per lane; LDS dest = wave-uniform base + lane*16.
__device__ __forceinline__ void gload_lds16(const void* g, void* l) {
  __builtin_amdgcn_global_load_lds(
      (const __attribute__((address_space(1))) void*)g,
      (__attribute__((address_space(3))) void*)l, 16, 0, 0);
}

// ---------------------------------------------------------------------------
// Kernel 0: f32 -> bf16 conversion (grid-stride, 16B loads x2 -> 16B store).
// ---------------------------------------------------------------------------
__global__ __launch_bounds__(256)
void cvt_bf16_kernel(const float* __restrict__ src, __bf16* __restrict__ dst,
                     long long n8)
{
  long long i = (long long)blockIdx.x * blockDim.x + threadIdx.x;
  const long long stride = (long long)gridDim.x * blockDim.x;
  for (; i < n8; i += stride) {
    const float4 a = *reinterpret_cast<const float4*>(src + i * 8);
    const float4 b = *reinterpret_cast<const float4*>(src + i * 8 + 4);
    *reinterpret_cast<bf16x8*>(dst + i * 8) = cvt8(a, b);
  }
}

// ---------------------------------------------------------------------------
// Kernel 1: FUSED policy+ref bf16-MFMA GEMM (logits = A[M,K] x W[V,K]^T) with
// per-row per-256-col-chunk reductions.
// grid = 2*gx*NC; after XCD remap, block PARITY selects policy vs ref.
// STAGING (r13, m97/m151 pattern): global_load_lds width=16 for BOTH A and W.
//   K-tile = 64 (one 128B LDS row per tile), SINGLE-buffered, 2 barriers per
//   tile: sync -> issue 6 gload_lds/thread -> sync (drains vmcnt) -> compute
//   2 k-halves x 16 MFMA. No staging VGPRs, no cvt/ds_write VALU; m151
//   measured 874 vs 646 TF for this staging choice at 128-class tiles.
// Swizzle per rule #21 (both-sides): LDS dest LINEAR (wave chunk 1KB, lane
//   l at +l*16 -> row chunk*8+(l>>3), phys granule l&7), global SOURCE
//   pre-swizzled (k-granule (l&7)^(l>>3)); reads use r10's proven formula
//   phys byte = row*128 + (((kh<<6)|(q<<4)) ^ ((row&7)<<4)) -> logical k.
// LDS: A 16 KB + W 32 KB + red 8 KB = 56 KB -> 2 blocks/CU.
// CVT=true fallback (f32 inputs): r10's reg-staged double-half pipeline.
// FULL: V % BN == 0 -> no column guards in epilogue.
// ---------------------------------------------------------------------------
template <bool CVT, bool FULL>
__global__ __launch_bounds__(512, 4)
void fused_gemm_reduce(const float* __restrict__ AfP, const float* __restrict__ WfP,
                       const float* __restrict__ AfR, const float* __restrict__ WfR,
                       const __bf16* __restrict__ AhP, const __bf16* __restrict__ WhP,
                       const __bf16* __restrict__ AhR, const __bf16* __restrict__ WhR,
                       float* __restrict__ partP, float* __restrict__ partR,
                       int M, int K, int V, int NC, int NL, int gx)
{
  __shared__ __align__(16) unsigned short lds_a[BM * 64];   // 16 KB
  __shared__ __align__(16) unsigned short lds_w[BN * 64];   // 32 KB
  __shared__ __align__(16) float4 lds_red[BM * 4];          // 8 KB

  const int tid  = threadIdx.x;
  const int lane = tid & 63;
  const int wave = tid >> 6;      // 0..7
  const int wm   = wave >> 2;     // 0..1  (M half)
  const int wn   = wave & 3;      // 0..3  (N quarter)
  const int l15  = lane & 15;
  const int q    = lane >> 4;     // 0..3

  // ---- XCD-aware block remap (bijective when nb % 8 == 0) + parity split ----
  const int nb  = gridDim.x;
  int wl = blockIdx.x;
  if ((nb & 7) == 0) wl = (wl & 7) * (nb >> 3) + (wl >> 3);
  const bool isPol = (wl & 1) == 0;     // even -> policy, odd -> ref
  const int  w2    = wl >> 1;
  const int  bx    = w2 % gx;
  const int  chunk = w2 / gx;
  const int  row0  = bx * BM;

  // uniform input selects
  const float*  Af = isPol ? AfP : AfR;
  const float*  Wf = isPol ? WfP : WfR;
  const __bf16* Ah = isPol ? AhP : AhR;
  const __bf16* Wh = isPol ? WhP : WhR;

  // ---- gload staging geometry: pre-swizzled global k-granule ----
  const int rsub = lane >> 3;                 // row within 8-row chunk
  const int srcg = ((lane & 7) ^ rsub) * 8;   // k element offset (granule*8)

  // ---- CVT-fallback reg-staging maps (r10) ----
  const int t3 = tid & 3;
  const int r4 = tid >> 2;        // 0..127
  const int stw = ((t3 * 16) ^ ((r4 & 7) << 4));
  const int sta = r4 * 128 + stw;
  const int aroF = min(row0 + r4, M - 1) * K + t3 * 8;

  // ---- fragment read byte offsets (k-half parity = bit 6; frag adds 2048) ----
  const int swzr  = ((q * 16) ^ ((l15 & 7) << 4));
  const int aoff0 = (wm * 64 + l15) * 128 + swzr;
  const int woff0 = (wn * 64 + l15) * 128 + swzr;

  // running per-row records (threads 0..127 own local row = tid)
  float rm = -INFINITY, rse = 0.f, rsum = 0.f;
  int   ridx = 0x7fffffff;

  for (int sub = 0; sub < NL; ++sub) {
    const int v0 = (chunk * NL + sub) * BN;
    if (v0 >= V) break;

    f32x4 acc[4][4];
#pragma unroll
    for (int i = 0; i < 4; ++i)
#pragma unroll
      for (int j = 0; j < 4; ++j) acc[i][j] = (f32x4){0.f, 0.f, 0.f, 0.f};

    if constexpr (!CVT) {
      // ================= gload_lds path (bf16 inputs) =================
      // A row bases (2 chunks) and W row bases (4 chunks), clamped
      const __bf16* asrc[2];
#pragma unroll
      for (int c = 0; c < 2; ++c) {
        const int r = (wave + c * 8) * 8 + rsub;            // 0..127
        asrc[c] = Ah + (size_t)min(row0 + r, M - 1) * K + srcg;
      }
      const __bf16* wsrc[4];
#pragma unroll
      for (int c = 0; c < 4; ++c) {
        const int r = (wave + c * 8) * 8 + rsub;            // 0..255
        wsrc[c] = Wh + (size_t)min(v0 + r, V - 1) * K + srcg;
      }

      for (int kt = 0; kt < K; kt += 64) {
        __syncthreads();   // all waves done reading previous tile
#pragma unroll
        for (int c = 0; c < 2; ++c)
          gload_lds16(asrc[c] + kt,
                      reinterpret_cast<char*>(lds_a) + (wave + c * 8) * 1024);
#pragma unroll
        for (int c = 0; c < 4; ++c)
          gload_lds16(wsrc[c] + kt,
                      reinterpret_cast<char*>(lds_w) + (wave + c * 8) * 1024);
        __syncthreads();   // drains vmcnt(0) -> tile resident

#pragma unroll
        for (int kh = 0; kh < 2; ++kh) {
          const int p = kh << 6;
          bf16x8 afr[4];
#pragma unroll
          for (int f = 0; f < 4; ++f)
            afr[f] = *reinterpret_cast<const bf16x8*>(
                reinterpret_cast<const char*>(lds_a) + (aoff0 ^ p) + f * 2048);
          __builtin_amdgcn_s_setprio(1);
#pragma unroll
          for (int fn = 0; fn < 4; ++fn) {
            bf16x8 wfr = *reinterpret_cast<const bf16x8*>(
                reinterpret_cast<const char*>(lds_w) + (woff0 ^ p) + fn * 2048);
#pragma unroll
            for (int fm = 0; fm < 4; ++fm)
              acc[fm][fn] = __builtin_amdgcn_mfma_f32_16x16x32_bf16(
                  afr[fm], wfr, acc[fm][fn], 0, 0, 0);
          }
          __builtin_amdgcn_s_setprio(0);
        }
      }
      __syncthreads();   // tile reads done before epilogue reuses lds_red
    } else {
      // ================= CVT fallback: r10 reg-staged pipeline =================
      const int NS = K / 32;
      int wro[2];
#pragma unroll
      for (int i = 0; i < 2; ++i)
        wro[i] = min(v0 + r4 + 128 * i, V - 1) * K + t3 * 8;

      float4 aF[2], wF[2][2];
      aF[0] = *reinterpret_cast<const float4*>(Af + aroF);
      aF[1] = *reinterpret_cast<const float4*>(Af + aroF + 4);
#pragma unroll
      for (int i = 0; i < 2; ++i) {
        wF[i][0] = *reinterpret_cast<const float4*>(Wf + wro[i]);
        wF[i][1] = *reinterpret_cast<const float4*>(Wf + wro[i] + 4);
      }
      *reinterpret_cast<bf16x8*>(reinterpret_cast<char*>(lds_a) + sta) = cvt8(aF[0], aF[1]);
#pragma unroll
      for (int i = 0; i < 2; ++i)
        *reinterpret_cast<bf16x8*>(reinterpret_cast<char*>(lds_w) + (r4 + 128 * i) * 128 + stw) =
            cvt8(wF[i][0], wF[i][1]);
      if (NS > 1) {
        aF[0] = *reinterpret_cast<const float4*>(Af + aroF + 32);
        aF[1] = *reinterpret_cast<const float4*>(Af + aroF + 32 + 4);
#pragma unroll
        for (int i = 0; i < 2; ++i) {
          wF[i][0] = *reinterpret_cast<const float4*>(Wf + wro[i] + 32);
          wF[i][1] = *reinterpret_cast<const float4*>(Wf + wro[i] + 32 + 4);
        }
      }
      bar_lgkm();

      for (int s = 0; s < NS; ++s) {
        const int p = (s & 1) << 6;
        bf16x8 afr[4];
#pragma unroll
        for (int f = 0; f < 4; ++f)
          afr[f] = *reinterpret_cast<const bf16x8*>(
              reinterpret_cast<const char*>(lds_a) + (aoff0 ^ p) + f * 2048);
        __builtin_amdgcn_s_setprio(1);
#pragma unroll
        for (int fn = 0; fn < 4; ++fn) {
          bf16x8 wfr = *reinterpret_cast<const bf16x8*>(
              reinterpret_cast<const char*>(lds_w) + (woff0 ^ p) + fn * 2048);
#pragma unroll
          for (int fm = 0; fm < 4; ++fm)
            acc[fm][fn] = __builtin_amdgcn_mfma_f32_16x16x32_bf16(
                afr[fm], wfr, acc[fm][fn], 0, 0, 0);
        }
        __builtin_amdgcn_s_setprio(0);

        if (s + 1 < NS) {
          const int p1 = ((s + 1) & 1) << 6;
          *reinterpret_cast<bf16x8*>(reinterpret_cast<char*>(lds_a) + (sta ^ p1)) =
              cvt8(aF[0], aF[1]);
#pragma unroll
          for (int i = 0; i < 2; ++i)
            *reinterpret_cast<bf16x8*>(
                reinterpret_cast<char*>(lds_w) + (((r4 + 128 * i) * 128 + stw) ^ p1)) =
                cvt8(wF[i][0], wF[i][1]);
          if (s + 2 < NS) {
            const int kf = (s + 2) * 32;
            aF[0] = *reinterpret_cast<const float4*>(Af + aroF + kf);
            aF[1] = *reinterpret_cast<const float4*>(Af + aroF + kf + 4);
#pragma unroll
            for (int i = 0; i < 2; ++i) {
              wF[i][0] = *reinterpret_cast<const float4*>(Wf + wro[i] + kf);
              wF[i][1] = *reinterpret_cast<const float4*>(Wf + wro[i] + kf + 4);
            }
          }
        }
        bar_lgkm();
      }
    }

    // ---- fused epilogue: per-row reduction over this 256-col sub-tile ----
    // C/D layout: col = lane&15, row = (lane>>4)*4 + reg  [verified m89/m91]
    // Max-first; ref blocks skip argmax + logit-sum (uniform branch).
#pragma unroll
    for (int fm = 0; fm < 4; ++fm) {
#pragma unroll
      for (int reg = 0; reg < 4; ++reg) {
        float lm = -INFINITY;
#pragma unroll
        for (int fn = 0; fn < 4; ++fn) {
          if (FULL || v0 + wn * 64 + fn * 16 + l15 < V)
            lm = fmaxf(lm, acc[fm][fn][reg]);
        }
#pragma unroll
        for (int d = 1; d < 16; d <<= 1) lm = fmaxf(lm, __shfl_xor(lm, d));
        // lm == exact row max (within this wave's 64-col tile)
        float se = 0.f, sm = 0.f; int li = 0x7fffffff;
#pragma unroll
        for (int fn = 0; fn < 4; ++fn) {
          const int v = v0 + wn * 64 + fn * 16 + l15;
          if (FULL || v < V) {
            const float x = acc[fm][fn][reg];
            se += __expf(x - lm);
            if (isPol) {
              sm += x;
              if (x == lm) li = min(li, v);
            }
          }
        }
        if (isPol) {
#pragma unroll
          for (int d = 1; d < 16; d <<= 1) {
            se += __shfl_xor(se, d);
            sm += __shfl_xor(sm, d);
            li  = min(li, __shfl_xor(li, d));
          }
        } else {
#pragma unroll
          for (int d = 1; d < 16; d <<= 1) se += __shfl_xor(se, d);
        }
        if (l15 == 0) {
          const int row = wm * 64 + fm * 16 + q * 4 + reg;
          lds_red[row * 4 + wn] = make_float4(lm, se, sm, __int_as_float(li));
        }
      }
    }
    __syncthreads();

    if (tid < BM) {
      float4 p0 = lds_red[tid * 4];
      float m = p0.x, se = p0.y, sm = p0.z; int idx = __float_as_int(p0.w);
#pragma unroll
      for (int j = 1; j < 4; ++j) {
        const float4 t = lds_red[tid * 4 + j];
        const int ti = __float_as_int(t.w);
        const float nm = fmaxf(m, t.x);
        se = se * sexp_fast(m - nm) + t.y * sexp_fast(t.x - nm);
        if (isPol) {
          sm += t.z;
          if (t.x > m || (t.x == m && ti < idx)) idx = ti;
        }
        m = nm;
      }
      const float nm = fmaxf(rm, m);
      rse = rse * sexp_fast(rm - nm) + se * sexp_fast(m - nm);
      if (isPol) {
        rsum += sm;
        if (m > rm || (m == rm && idx < ridx)) ridx = idx;
      }
      rm = nm;
    }
    __syncthreads();  // lds_red / lds tiles free for next sub
  }

  if (tid < BM) {
    const int row = row0 + tid;
    if (row < M) {
      if (isPol) {
        reinterpret_cast<float4*>(partP)[(size_t)row * NC + chunk] =
            make_float4(rm, rse, rsum, __int_as_float(ridx));
      } else {
        reinterpret_cast<float2*>(partR)[(size_t)row * NC + chunk] =
            make_float2(rm, rse);
      }
    }
  }
}

// ---------------------------------------------------------------------------
// Kernel 2: per-row combine of chunk partials + gathered ref dot (f32 exact).
// Writes rowtab[row] = {tok_lp, kl, mean_v(log_probs_row), 0}
// grid = (M), block = 256
// ---------------------------------------------------------------------------
__global__ __launch_bounds__(256)
void combine_kernel(const float4* __restrict__ partP,
                    const float2* __restrict__ partR,
                    const float* __restrict__ refA,
                    const float* __restrict__ refW,
                    float4* __restrict__ rowtab,
                    int M, int K, int V, int NC)
{
  const int row = blockIdx.x;
  const int tid = threadIdx.x;

  __shared__ float redf[256];
  __shared__ int   redi[256];
  __shared__ float s_M, s_SE, s_SUM, s_Mr, s_SEr, s_dot;
  __shared__ int   s_idx;

  float m = -INFINITY, se = 0.f, sm = 0.f; int idx = 0x7fffffff;
  for (int i = tid; i < NC; i += 256) {
    float4 p = partP[(size_t)row * NC + i];
    int pi = __float_as_int(p.w);
    float nm = fmaxf(m, p.x);
    se = se * sexp(m - nm) + p.y * sexp(p.x - nm);
    if (p.x > m || (p.x == m && pi < idx)) idx = pi;
    m = nm;
    sm += p.z;
  }
  redf[tid] = m; redi[tid] = idx;
  __syncthreads();
  for (int s = 128; s > 0; s >>= 1) {
    if (tid < s) {
      float om = redf[tid + s]; int oi = redi[tid + s];
      if (om > redf[tid] || (om == redf[tid] && oi < redi[tid])) { redf[tid] = om; redi[tid] = oi; }
    }
    __syncthreads();
  }
  if (tid == 0) { s_M = redf[0]; s_idx = redi[0]; }
  __syncthreads();
  const float Mp = s_M; const int chosen = s_idx;

  float contrib = se * sexp(m - Mp);
  __syncthreads();
  redf[tid] = contrib; __syncthreads();
  for (int s = 128; s > 0; s >>= 1) { if (tid < s) redf[tid] += redf[tid + s]; __syncthreads(); }
  if (tid == 0) s_SE = redf[0];
  __syncthreads();
  redf[tid] = sm; __syncthreads();
  for (int s = 128; s > 0; s >>= 1) { if (tid < s) redf[tid] += redf[tid + s]; __syncthreads(); }
  if (tid == 0) s_SUM = redf[0];
  __syncthreads();

  float mr = -INFINITY, ser = 0.f;
  for (int i = tid; i < NC; i += 256) {
    float2 p = partR[(size_t)row * NC + i];
    float nm = fmaxf(mr, p.x);
    ser = ser * sexp(mr - nm) + p.y * sexp(p.x - nm);
    mr = nm;
  }
  redf[tid] = mr; __syncthreads();
  for (int s = 128; s > 0; s >>= 1) { if (tid < s) redf[tid] = fmaxf(redf[tid], redf[tid + s]); __syncthreads(); }
  if (tid == 0) s_Mr = redf[0];
  __syncthreads();
  const float Mr = s_Mr;
  float contribr = ser * sexp(mr - Mr);
  __syncthreads();
  redf[tid] = contribr; __syncthreads();
  for (int s = 128; s > 0; s >>= 1) { if (tid < s) redf[tid] += redf[tid + s]; __syncthreads(); }
  if (tid == 0) s_SEr = redf[0];
  __syncthreads();

  float dp = 0.f;
  const float* ar = refA + (size_t)row * K;
  const float* wr = refW + (size_t)chosen * K;
  for (int j = tid * 4; j < K; j += 256 * 4) {
    float4 x = *reinterpret_cast<const float4*>(ar + j);
    float4 y = *reinterpret_cast<const float4*>(wr + j);
    dp = fmaf(x.x, y.x, dp);
    dp = fmaf(x.y, y.y, dp);
    dp = fmaf(x.z, y.z, dp);
    dp = fmaf(x.w, y.w, dp);
  }
  __syncthreads();
  redf[tid] = dp; __syncthreads();
  for (int s = 128; s > 0; s >>= 1) { if (tid < s) redf[tid] += redf[tid + s]; __syncthreads(); }
  if (tid == 0) s_dot = redf[0];
  __syncthreads();

  if (tid == 0) {
    float lse     = Mp + logf(s_SE);
    float tok     = Mp - lse;
    float ref_lse = Mr + logf(s_SEr);
    float ref_tok = s_dot - ref_lse;
    float d  = ref_tok - tok;
    float kl = expm1f(d) - d;
    float rm3 = s_SUM / (float)V - lse;
    rowtab[row] = make_float4(tok, kl, rm3, 0.f);
  }
}

// ---------------------------------------------------------------------------
// Kernel 3: final reduction over rows -> 5 scalar outputs. grid=(1), block=256
// ---------------------------------------------------------------------------
__global__ __launch_bounds__(256)
void final_kernel(const float4* __restrict__ rowtab,
                  const float* __restrict__ mask,
                  const float* __restrict__ rewards,
                  float* __restrict__ out,
                  int M, int B, int T)
{
  const int tid = threadIdx.x;
  __shared__ float redf[256];
  __shared__ float s_mean, s_m3, s_var;
  __shared__ float s_kl[16], s_cnt[16];

  float st = 0.f, sm3 = 0.f;
  for (int r = tid; r < M; r += 256) {
    float4 v = rowtab[r];
    st += v.x; sm3 += v.z;
  }
  redf[tid] = st; __syncthreads();
  for (int s = 128; s > 0; s >>= 1) { if (tid < s) redf[tid] += redf[tid + s]; __syncthreads(); }
  if (tid == 0) s_mean = redf[0] / (float)M;
  __syncthreads();
  redf[tid] = sm3; __syncthreads();
  for (int s = 128; s > 0; s >>= 1) { if (tid < s) redf[tid] += redf[tid + s]; __syncthreads(); }
  if (tid == 0) s_m3 = redf[0] / (float)M;
  __syncthreads();

  const float mean = s_mean;
  float sv = 0.f;
  for (int r = tid; r < M; r += 256) { float d = rowtab[r].x - mean; sv = fmaf(d, d, sv); }
  __syncthreads();
  redf[tid] = sv; __syncthreads();
  for (int s = 128; s > 0; s >>= 1) { if (tid < s) redf[tid] += redf[tid + s]; __syncthreads(); }
  if (tid == 0) s_var = redf[0];
  __syncthreads();

  const int nb = B < 16 ? B : 16;
  for (int b = 0; b < nb; ++b) {
    float lk = 0.f, lc = 0.f;
    for (int t = tid; t < T; t += 256) {
      int r = b * T + t;
      float mk = mask[r];
      lk = fmaf(rowtab[r].y, mk, lk);
      lc += mk;
    }
    __syncthreads();
    redf[tid] = lk; __syncthreads();
    for (int s = 128; s > 0; s >>= 1) { if (tid < s) redf[tid] += redf[tid + s]; __syncthreads(); }
    if (tid == 0) s_kl[b] = redf[0];
    __syncthreads();
    redf[tid] = lc; __syncthreads();
    for (int s = 128; s > 0; s >>= 1) { if (tid < s) redf[tid] += redf[tid + s]; __syncthreads(); }
    if (tid == 0) s_cnt[b] = redf[0];
    __syncthreads();
  }

  if (tid == 0) {
    float rmean = 0.f;
    for (int b = 0; b < B; ++b) rmean += rewards[b];
    rmean /= (float)B;
    float rv = 0.f;
    for (int b = 0; b < B; ++b) { float d = rewards[b] - rmean; rv += d * d; }
    float rstd = sqrtf(rv / (float)(B > 1 ? B - 1 : 1));

    float loss = 0.f, m4n = 0.f, m4d = 0.f;
    for (int b = 0; b < nb; ++b) {
      float adv  = (rewards[b] - rmean) / (rstd + 1e-8f);
      float cnt  = s_cnt[b];
      float seql = fmaxf(cnt, 1.0f);
      loss += (-adv * cnt + GRPO_BETA * s_kl[b]) / seql;
      m4n += s_kl[b];
      m4d += cnt;
    }
    loss /= (float)B;

    out[0] = loss;
    out[1] = s_mean;
    out[2] = sqrtf(s_var / (float)(M - 1));
    out[3] = s_m3;
    out[4] = m4n / m4d;
  }
}

// ---------------------------------------------------------------------------
extern "C" void kernel_launch(void* const* d_in, const int* in_sizes, int n_in,
                              void* d_out, int out_size, void* d_ws, size_t ws_size,
                              hipStream_t stream)
{
  if (n_in < 6) return;
  const float* A       = (const float*)d_in[0];
  const float* W       = (const float*)d_in[1];
  const float* mask    = (const float*)d_in[2];
  const float* rewards = (const float*)d_in[3];
  const float* rA      = (const float*)d_in[4];
  const float* rW      = (const float*)d_in[5];

  const int M = in_sizes[2];            // B*T
  const int B = in_sizes[3];
  const int T = M / B;
  const int K = in_sizes[0] / M;        // H
  const int V = in_sizes[1] / K;

  const int gx = (M + BM - 1) / BM;
  const bool full = (V % BN) == 0;

  // ---- workspace budgeting ----
  const size_t aBytes = (size_t)M * K * sizeof(__bf16);
  const size_t wBytes = (size_t)V * K * sizeof(__bf16);
  auto partBytes = [&](int nl) -> size_t {
    int nc = (V + BN * nl - 1) / (BN * nl);
    return (size_t)M * nc * 16 + (size_t)M * nc * 8 + (size_t)M * 16;
  };

  int NL = 1;
  bool canPrep = false;
  if (K % 64 == 0) {   // gload path stages K-tiles of 64
    for (int nl = 1; nl <= 1024; nl <<= 1) {
      size_t pb = (partBytes(nl) + 255) & ~(size_t)255;
      if (pb + 2 * aBytes + 2 * wBytes <= ws_size) { NL = nl; canPrep = true; break; }
    }
  }
  if (!canPrep) {
    NL = 1;
    while (partBytes(NL) > ws_size && NL < 1024) NL <<= 1;
  }
  const int NC = (V + BN * NL - 1) / (BN * NL);

  float* partP  = (float*)d_ws;                    // M*NC float4
  float* partR  = partP + (size_t)M * NC * 4;      // M*NC float2
  float* rowtab = partR + (size_t)M * NC * 2;      // M float4

  dim3 g1(2 * gx * NC), b1(512);

  if (canPrep) {
    size_t pb = (partBytes(NL) + 255) & ~(size_t)255;
    __bf16* Ab  = (__bf16*)((char*)d_ws + pb);
    __bf16* rAb = Ab  + (size_t)M * K;
    __bf16* Wb  = rAb + (size_t)M * K;
    __bf16* rWb = Wb  + (size_t)V * K;

    const long long nA8 = (long long)M * K / 8;
    const long long nW8 = (long long)V * K / 8;
    cvt_bf16_kernel<<<dim3(512),  dim3(256), 0, stream>>>(A,  Ab,  nA8);
    cvt_bf16_kernel<<<dim3(512),  dim3(256), 0, stream>>>(rA, rAb, nA8);
    cvt_bf16_kernel<<<dim3(2048), dim3(256), 0, stream>>>(W,  Wb,  nW8);
    cvt_bf16_kernel<<<dim3(2048), dim3(256), 0, stream>>>(rW, rWb, nW8);

    if (full) {
      fused_gemm_reduce<false, true ><<<g1, b1, 0, stream>>>(
          nullptr, nullptr, nullptr, nullptr, Ab, Wb, rAb, rWb,
          partP, partR, M, K, V, NC, NL, gx);
    } else {
      fused_gemm_reduce<false, false><<<g1, b1, 0, stream>>>(
          nullptr, nullptr, nullptr, nullptr, Ab, Wb, rAb, rWb,
          partP, partR, M, K, V, NC, NL, gx);
    }
  } else {
    if (full) {
      fused_gemm_reduce<true , true ><<<g1, b1, 0, stream>>>(
          A, W, rA, rW, nullptr, nullptr, nullptr, nullptr,
          partP, partR, M, K, V, NC, NL, gx);
    } else {
      fused_gemm_reduce<true , false><<<g1, b1, 0, stream>>>(
          A, W, rA, rW, nullptr, nullptr, nullptr, nullptr,
          partP, partR, M, K, V, NC, NL, gx);
    }
  }

  combine_kernel<<<dim3(M), dim3(256), 0, stream>>>(
      (const float4*)partP, (const float2*)partR, rA, rW, (float4*)rowtab, M, K, V, NC);
  final_kernel<<<dim3(1), dim3(256), 0, stream>>>(
      (const float4*)rowtab, mask, rewards, (float*)d_out, M, B, T);
}